// Round 4
// baseline (133.880 us; speedup 1.0000x reference)
//
#include <hip/hip_runtime.h>

// ARMA posterior: per chain c in DP=32, sample s:
//   A[t]     = sigmoid(a_raw[t-1, dim_idx[d]])   (A[0]=0; same for all p in d)
//   sv[t]    = softplus(s_raw[t, dim_idx[d], p])
//   z        = (1-A)*m[t,di,p] + sv*noise
//   param[t] = z + A*param[t-1]
//   lp[t]    = -log(sv) - 0.5*log2pi - 0.5*noise^2
//
// R9: traffic is ideal (R8: FETCH 34MB, WRITE 66MB) but BW stuck at 2.4TB/s
// with VGPR_Count=28 -> the (1024,8) launch bound starved the allocator and
// loads were never hoisted (~2 in flight/thread, latency-bound). Fix: batch
// ALL phase-0 loads into explicit arrays before any compute (24 vector + 8
// scalar loads in flight = 12KB/wave), drop the min-wave bound (128-VGPR cap
// from 1024-thd block is plenty at 1 block/CU -- fills hit 6.4TB/s at 8.5%
// occupancy, so in-flight bytes, not occupancy, is what buys BW).
#define T_DIM 1024
#define D_DIM 4
#define P_DIM 8
#define S_DIM 256
#define DP 32
#define TDP (T_DIM * DP)      // 32768 per sample
#define LOG2PI_F 1.8378770664093453f

typedef float vf2 __attribute__((ext_vector_type(2)));

__device__ __forceinline__ float sigmoid_fast(float x) {
    return __builtin_amdgcn_rcpf(1.0f + __expf(-x));  // x=-87 -> rcp(inf) = 0
}

__global__ __launch_bounds__(1024) void fused_scan(
    const float* __restrict__ noise,
    const float* __restrict__ m,
    const float* __restrict__ s_raw,
    const float* __restrict__ a_raw,
    const int* __restrict__ dim_idx,
    float* __restrict__ param_out,
    float* __restrict__ lp_out)
{
    const int tid = threadIdx.x;
    const int pc  = tid & 7;           // chain-pair 0..7 (2 chains each)
    const int cj  = tid >> 3;          // time chunk 0..127 (8 steps each)
    const int cjw = cj & 7;            // chunk within wave
    const int wg  = tid >> 6;          // wave 0..15

    const int half = blockIdx.x & 1;   // which 16 of the 32 chains
    const int s    = blockIdx.x >> 1;  // sample

    const int c0 = half * 16 + pc * 2; // first chain of this thread
    const int d  = c0 >> 3;            // output dim 0..3
    const int p0 = c0 & 7;             // first of 2 consecutive p
    const int di = dim_idx[d];

    __shared__ float wtp[16][16];      // wave-total p (per chain)
    __shared__ float wtm8[16][8];      // wave-total M (scalar per pair)
    __shared__ float wci[16][16];      // exclusive carry-in per wave

    const size_t sbase = (size_t)s * TDP;
    const int    off0  = cj * 8 * DP + c0;

    // ---- Phase 0a: BATCH all loads (24 vector + 8 scalar in flight).
    vf2   n[8], mv[8], sr[8];
    float ar[8];
#pragma unroll
    for (int k = 0; k < 8; ++k) {
        const int o = off0 + k * DP;
        n[k] = __builtin_nontemporal_load((const vf2*)(noise + sbase + o));
    }
#pragma unroll
    for (int k = 0; k < 8; ++k) {
        const int t = cj * 8 + k;
        mv[k] = *(const vf2*)(m     + (t * D_DIM + di) * P_DIM + p0);
        sr[k] = *(const vf2*)(s_raw + (t * D_DIM + di) * P_DIM + p0);
        // pre-sigmoid A input; -87 -> sigmoid exactly 0 (t==0 case)
        ar[k] = (t > 0) ? a_raw[(t - 1) * D_DIM + di] : -87.0f;
    }

    // ---- Phase 0b: local 8-step scan over 2 chains; M-part scalar
    vf2   pl[8];
    float Mk[8];
    vf2   rp = (vf2){0.f, 0.f};
    float rm = 1.0f;
#pragma unroll
    for (int k = 0; k < 8; ++k) {
        const int o = off0 + k * DP;
        const float A   = sigmoid_fast(ar[k]);
        const float oma = 1.0f - A;

        // softplus + negative-log-sv per chain
        vf2 sv, nl;
        sv.x = __logf(1.0f + __expf(sr[k].x));  nl.x = -__logf(sv.x) - 0.5f * LOG2PI_F;
        sv.y = __logf(1.0f + __expf(sr[k].y));  nl.y = -__logf(sv.y) - 0.5f * LOG2PI_F;

        vf2 lp;
        lp.x = nl.x - 0.5f * n[k].x * n[k].x;
        lp.y = nl.y - 0.5f * n[k].y * n[k].y;
        *(vf2*)(lp_out + sbase + o) = lp;

        vf2 z;
        z.x = oma * mv[k].x + sv.x * n[k].x;
        z.y = oma * mv[k].y + sv.y * n[k].y;

        rp.x = z.x + A * rp.x;
        rp.y = z.y + A * rp.y;
        rm  *= A;
        pl[k] = rp;
        Mk[k] = rm;
    }

    // ---- Phase A: inclusive shfl-scan over 8 chunks within each wave
    //      combine(older(p1,m1), newer(p2,m2)) = (p2 + m2*p1, m1*m2)
#pragma unroll
    for (int off = 1; off < 8; off <<= 1) {
        const int dd = off * 8;        // lanes per chunk step
        vf2 pp;
        pp.x = __shfl_up(rp.x, dd, 64);
        pp.y = __shfl_up(rp.y, dd, 64);
        const float pm = __shfl_up(rm, dd, 64);
        if (cjw >= off) {
            rp.x += rm * pp.x;
            rp.y += rm * pp.y;
            rm *= pm;
        }
    }

    // ---- Phase B: wave totals -> serial scan over 16 waves (16 lanes)
    if (cjw == 7) {
        *(vf2*)&wtp[wg][pc * 2] = rp;
        wtm8[wg][pc] = rm;
    }
    __syncthreads();
    if (tid < 16) {
        float c = 0.0f;
#pragma unroll
        for (int g = 0; g < 16; ++g) {
            wci[g][tid] = c;
            c = wtp[g][tid] + wtm8[g][tid >> 1] * c;
        }
    }
    __syncthreads();

    // ---- Phase C: per-thread carry-in = excl-in-wave composed on wave carry
    vf2 ep;
    ep.x = __shfl_up(rp.x, 8, 64);
    ep.y = __shfl_up(rp.y, 8, 64);
    float em = __shfl_up(rm, 8, 64);
    if (cjw == 0) {
        ep = (vf2){0.f, 0.f};
        em = 1.0f;
    }
    const vf2 ci = *(const vf2*)&wci[wg][pc * 2];
    vf2 carry;
    carry.x = ep.x + em * ci.x;
    carry.y = ep.y + em * ci.y;

#pragma unroll
    for (int k = 0; k < 8; ++k) {
        const int o = off0 + k * DP;
        vf2 pv;
        pv.x = pl[k].x + Mk[k] * carry.x;
        pv.y = pl[k].y + Mk[k] * carry.y;
        *(vf2*)(param_out + sbase + o) = pv;
    }
}

// ---------------------------------------------------------------------------
extern "C" void kernel_launch(void* const* d_in, const int* in_sizes, int n_in,
                              void* d_out, int out_size, void* d_ws, size_t ws_size,
                              hipStream_t stream)
{
    // 0:y 1:age 2:m(T,D,P) 3:s_raw(T,D,P) 4:a_raw(T-1,D,1) 5:noise(S,T,D,P)
    // 6:cond_sample 7:dim_idx(D) 8:compute_log_prob
    const float* m      = (const float*)d_in[2];
    const float* s_raw  = (const float*)d_in[3];
    const float* a_raw  = (const float*)d_in[4];
    const float* noise  = (const float*)d_in[5];
    const int*   dimidx = (const int*)d_in[7];

    float* param_out = (float*)d_out;
    float* lp_out    = param_out + (size_t)S_DIM * TDP;

    fused_scan<<<S_DIM * 2, 1024, 0, stream>>>(noise, m, s_raw, a_raw, dimidx,
                                               param_out, lp_out);
}

// Round 5
// 131.828 us; speedup vs baseline: 1.0156x; 1.0156x over previous
//
#include <hip/hip_runtime.h>

// ARMA posterior: per chain c in DP=32, sample s:
//   A[t]     = sigmoid(a_raw[t-1, dim_idx[d]])   (A[0]=0; same for all p in d)
//   sv[t]    = softplus(s_raw[t, dim_idx[d], p])
//   z        = (1-A)*m[t,di,p] + sv*noise
//   param[t] = z + A*param[t-1]
//   lp[t]    = -log(sv) - 0.5*log2pi - 0.5*noise^2
//
// R10: R9's batched loads were re-sunk by the machine scheduler (VGPR=36
// proves ~2 loads in flight, latency-bound at 1.6-2.4 TB/s while traffic is
// already ideal). Fix: __builtin_amdgcn_sched_barrier(0) after the load
// batch -- nothing may cross, so all 32 loads issue before any compute
// (12KB in flight/wave). lp is computed into registers and stored AFTER the
// local scan so no store sits in the load-consume vmcnt window; the lp
// stores then drain under the lgkmcnt-bound shuffle phases.
#define T_DIM 1024
#define D_DIM 4
#define P_DIM 8
#define S_DIM 256
#define DP 32
#define TDP (T_DIM * DP)      // 32768 per sample
#define LOG2PI_F 1.8378770664093453f

typedef float vf2 __attribute__((ext_vector_type(2)));

__device__ __forceinline__ float sigmoid_fast(float x) {
    return __builtin_amdgcn_rcpf(1.0f + __expf(-x));  // x=-87 -> rcp(inf) = 0
}

__global__ __launch_bounds__(1024) void fused_scan(
    const float* __restrict__ noise,
    const float* __restrict__ m,
    const float* __restrict__ s_raw,
    const float* __restrict__ a_raw,
    const int* __restrict__ dim_idx,
    float* __restrict__ param_out,
    float* __restrict__ lp_out)
{
    const int tid = threadIdx.x;
    const int pc  = tid & 7;           // chain-pair 0..7 (2 chains each)
    const int cj  = tid >> 3;          // time chunk 0..127 (8 steps each)
    const int cjw = cj & 7;            // chunk within wave
    const int wg  = tid >> 6;          // wave 0..15

    const int half = blockIdx.x & 1;   // which 16 of the 32 chains
    const int s    = blockIdx.x >> 1;  // sample

    const int c0 = half * 16 + pc * 2; // first chain of this thread
    const int d  = c0 >> 3;            // output dim 0..3
    const int p0 = c0 & 7;             // first of 2 consecutive p
    const int di = dim_idx[d];

    __shared__ float wtp[16][16];      // wave-total p (per chain)
    __shared__ float wtm8[16][8];      // wave-total M (scalar per pair)
    __shared__ float wci[16][16];      // exclusive carry-in per wave

    const size_t sbase = (size_t)s * TDP;
    const int    off0  = cj * 8 * DP + c0;

    // ---- Phase 0a: BATCH all loads; sched_barrier pins them above compute.
    vf2   n[8], mv[8], sr[8];
    float ar[8];
#pragma unroll
    for (int k = 0; k < 8; ++k) {
        const int o = off0 + k * DP;
        n[k] = __builtin_nontemporal_load((const vf2*)(noise + sbase + o));
    }
#pragma unroll
    for (int k = 0; k < 8; ++k) {
        const int t = cj * 8 + k;
        mv[k] = *(const vf2*)(m     + (t * D_DIM + di) * P_DIM + p0);
        sr[k] = *(const vf2*)(s_raw + (t * D_DIM + di) * P_DIM + p0);
        // pre-sigmoid A input; -87 -> sigmoid exactly 0 (t==0 case)
        ar[k] = (t > 0) ? a_raw[(t - 1) * D_DIM + di] : -87.0f;
    }
    __builtin_amdgcn_sched_barrier(0);   // all 32 loads issue before any compute

    // ---- Phase 0b: local 8-step scan over 2 chains; lp into registers.
    vf2   pl[8], lp[8];
    float Mk[8];
    vf2   rp = (vf2){0.f, 0.f};
    float rm = 1.0f;
#pragma unroll
    for (int k = 0; k < 8; ++k) {
        const float A   = sigmoid_fast(ar[k]);
        const float oma = 1.0f - A;

        // softplus + negative-log-sv per chain
        vf2 sv, nl;
        sv.x = __logf(1.0f + __expf(sr[k].x));  nl.x = -__logf(sv.x) - 0.5f * LOG2PI_F;
        sv.y = __logf(1.0f + __expf(sr[k].y));  nl.y = -__logf(sv.y) - 0.5f * LOG2PI_F;

        lp[k].x = nl.x - 0.5f * n[k].x * n[k].x;
        lp[k].y = nl.y - 0.5f * n[k].y * n[k].y;

        vf2 z;
        z.x = oma * mv[k].x + sv.x * n[k].x;
        z.y = oma * mv[k].y + sv.y * n[k].y;

        rp.x = z.x + A * rp.x;
        rp.y = z.y + A * rp.y;
        rm  *= A;
        pl[k] = rp;
        Mk[k] = rm;
    }

    // ---- lp stores AFTER the scan loop: they drain under the shuffle phases
#pragma unroll
    for (int k = 0; k < 8; ++k) {
        const int o = off0 + k * DP;
        *(vf2*)(lp_out + sbase + o) = lp[k];
    }

    // ---- Phase A: inclusive shfl-scan over 8 chunks within each wave
    //      combine(older(p1,m1), newer(p2,m2)) = (p2 + m2*p1, m1*m2)
#pragma unroll
    for (int off = 1; off < 8; off <<= 1) {
        const int dd = off * 8;        // lanes per chunk step
        vf2 pp;
        pp.x = __shfl_up(rp.x, dd, 64);
        pp.y = __shfl_up(rp.y, dd, 64);
        const float pm = __shfl_up(rm, dd, 64);
        if (cjw >= off) {
            rp.x += rm * pp.x;
            rp.y += rm * pp.y;
            rm *= pm;
        }
    }

    // ---- Phase B: wave totals -> serial scan over 16 waves (16 lanes)
    if (cjw == 7) {
        *(vf2*)&wtp[wg][pc * 2] = rp;
        wtm8[wg][pc] = rm;
    }
    __syncthreads();
    if (tid < 16) {
        float c = 0.0f;
#pragma unroll
        for (int g = 0; g < 16; ++g) {
            wci[g][tid] = c;
            c = wtp[g][tid] + wtm8[g][tid >> 1] * c;
        }
    }
    __syncthreads();

    // ---- Phase C: per-thread carry-in = excl-in-wave composed on wave carry
    vf2 ep;
    ep.x = __shfl_up(rp.x, 8, 64);
    ep.y = __shfl_up(rp.y, 8, 64);
    float em = __shfl_up(rm, 8, 64);
    if (cjw == 0) {
        ep = (vf2){0.f, 0.f};
        em = 1.0f;
    }
    const vf2 ci = *(const vf2*)&wci[wg][pc * 2];
    vf2 carry;
    carry.x = ep.x + em * ci.x;
    carry.y = ep.y + em * ci.y;

#pragma unroll
    for (int k = 0; k < 8; ++k) {
        const int o = off0 + k * DP;
        vf2 pv;
        pv.x = pl[k].x + Mk[k] * carry.x;
        pv.y = pl[k].y + Mk[k] * carry.y;
        *(vf2*)(param_out + sbase + o) = pv;
    }
}

// ---------------------------------------------------------------------------
extern "C" void kernel_launch(void* const* d_in, const int* in_sizes, int n_in,
                              void* d_out, int out_size, void* d_ws, size_t ws_size,
                              hipStream_t stream)
{
    // 0:y 1:age 2:m(T,D,P) 3:s_raw(T,D,P) 4:a_raw(T-1,D,1) 5:noise(S,T,D,P)
    // 6:cond_sample 7:dim_idx(D) 8:compute_log_prob
    const float* m      = (const float*)d_in[2];
    const float* s_raw  = (const float*)d_in[3];
    const float* a_raw  = (const float*)d_in[4];
    const float* noise  = (const float*)d_in[5];
    const int*   dimidx = (const int*)d_in[7];

    float* param_out = (float*)d_out;
    float* lp_out    = param_out + (size_t)S_DIM * TDP;

    fused_scan<<<S_DIM * 2, 1024, 0, stream>>>(noise, m, s_raw, a_raw, dimidx,
                                               param_out, lp_out);
}

// Round 6
// 113.710 us; speedup vs baseline: 1.1774x; 1.1593x over previous
//
#include <hip/hip_runtime.h>

// ARMA posterior: per chain c in DP=32, sample s:
//   A[t]     = sigmoid(a_raw[t-1, dim_idx[d]])   (A[0]=0; same for all p in d)
//   sv[t]    = softplus(s_raw[t, dim_idx[d], p])
//   z        = (1-A)*m[t,di,p] + sv*noise
//   param[t] = z + A*param[t-1]
//   lp[t]    = -log(sv) - 0.5*log2pi - 0.5*noise^2
//
// R11: R9/R10 proved hipcc will not keep VGPR-destination loads in flight
// (batch + sched_barrier both defeated; VGPR stuck at 36, 2.46 TB/s).
// Switch the HBM-bound stream (noise) to __builtin_amdgcn_global_load_lds:
// async DMA into LDS, no dest VGPRs, cannot be sunk/spilled. Each wave
// issues its full 8-step noise tile (8 x 1KB DMA) then waits vmcnt(0) once;
// 16 waves x 8KB = 128KB in flight per CU >> 9KB Little's-law need.
// Structure reverted to R6's vf4/qc layout (128B per 8 lanes, best measured).
// Local prefix pl[k] overwrites the consumed noise LDS slot so persistent
// VGPR stays low; phase C reads it back. m/s_raw/a_raw are L2-hot, in-loop.
#define T_DIM 1024
#define D_DIM 4
#define P_DIM 8
#define S_DIM 256
#define DP 32
#define TDP (T_DIM * DP)      // 32768 per sample
#define LOG2PI_F 1.8378770664093453f

typedef float vf4 __attribute__((ext_vector_type(4)));

__device__ __forceinline__ float sigmoid_fast(float x) {
    return __builtin_amdgcn_rcpf(1.0f + __expf(-x));
}

__global__ __launch_bounds__(1024) void fused_scan(
    const float* __restrict__ noise,
    const float* __restrict__ m,
    const float* __restrict__ s_raw,
    const float* __restrict__ a_raw,
    const int* __restrict__ dim_idx,
    float* __restrict__ param_out,
    float* __restrict__ lp_out)
{
    const int tid  = threadIdx.x;
    const int qc   = tid & 7;          // chain quad 0..7 (4 chains each)
    const int cj   = tid >> 3;         // time chunk 0..127 (8 steps each)
    const int cjw  = cj & 7;           // chunk within wave
    const int wg   = tid >> 6;         // wave 0..15
    const int lane = tid & 63;

    const int d  = qc >> 1;            // output dim 0..3
    const int p0 = (qc & 1) * 4;       // first of 4 consecutive p
    const int di = dim_idx[d];

    // dynamic LDS: per-wave noise tile, [wave][k][lane] * 4 floats = 128 KB
    extern __shared__ __align__(16) float nls[];
    __shared__ float wtp[16][32];      // wave-total p (per chain)
    __shared__ float wtm8[16][8];      // wave-total M (scalar per quad)
    __shared__ float wci[16][32];      // exclusive carry-in per wave

    const size_t sbase = (size_t)blockIdx.x * TDP;
    const int    off0  = cj * 8 * DP + qc * 4;

    float* lbase = nls + wg * 2048;    // this wave's 8KB region

    // ---- Phase 0a: DMA the wave's entire noise tile (8 x 1KB in flight).
    // Dest = wave-uniform base + lane*16; global src per-lane. Lane L
    // (= cjw*8+qc) reads 16B at off0+k*DP which is exactly slot lane*16.
#pragma unroll
    for (int k = 0; k < 8; ++k) {
        const float* g = noise + sbase + off0 + (size_t)k * DP;
        __builtin_amdgcn_global_load_lds(
            (const __attribute__((address_space(1))) void*)g,
            (__attribute__((address_space(3))) void*)(lbase + k * 256),
            16, 0, 0);
    }
    asm volatile("s_waitcnt vmcnt(0)" ::: "memory");

    // ---- Phase 0b: local 8-step scan over 4 chains out of LDS.
    float Mk[8];
    vf4   rp = (vf4){0.f, 0.f, 0.f, 0.f};
    float rm = 1.0f;
#pragma unroll
    for (int k = 0; k < 8; ++k) {
        const int t = cj * 8 + k;
        const int o = off0 + k * DP;
        const vf4 n  = *(const vf4*)(lbase + k * 256 + lane * 4);
        const vf4 mv = *(const vf4*)(m     + (t * D_DIM + di) * P_DIM + p0);
        const vf4 sr = *(const vf4*)(s_raw + (t * D_DIM + di) * P_DIM + p0);

        float A = 0.0f;
        if (t > 0) A = sigmoid_fast(a_raw[(t - 1) * D_DIM + di]);
        const float oma = 1.0f - A;

        // softplus + negative-log-sv per chain
        vf4 sv, nl;
        sv.x = __logf(1.0f + __expf(sr.x));  nl.x = -__logf(sv.x) - 0.5f * LOG2PI_F;
        sv.y = __logf(1.0f + __expf(sr.y));  nl.y = -__logf(sv.y) - 0.5f * LOG2PI_F;
        sv.z = __logf(1.0f + __expf(sr.z));  nl.z = -__logf(sv.z) - 0.5f * LOG2PI_F;
        sv.w = __logf(1.0f + __expf(sr.w));  nl.w = -__logf(sv.w) - 0.5f * LOG2PI_F;

        vf4 lp;
        lp.x = nl.x - 0.5f * n.x * n.x;
        lp.y = nl.y - 0.5f * n.y * n.y;
        lp.z = nl.z - 0.5f * n.z * n.z;
        lp.w = nl.w - 0.5f * n.w * n.w;
        *(vf4*)(lp_out + sbase + o) = lp;   // fire-and-forget

        vf4 z;
        z.x = oma * mv.x + sv.x * n.x;
        z.y = oma * mv.y + sv.y * n.y;
        z.z = oma * mv.z + sv.z * n.z;
        z.w = oma * mv.w + sv.w * n.w;

        rp.x = z.x + A * rp.x;
        rp.y = z.y + A * rp.y;
        rp.z = z.z + A * rp.z;
        rp.w = z.w + A * rp.w;
        rm  *= A;
        Mk[k] = rm;
        // local prefix overwrites the consumed noise slot (keeps VGPR low)
        *(vf4*)(lbase + k * 256 + lane * 4) = rp;
    }

    // ---- Phase A: inclusive shfl-scan over 8 chunks within each wave
    //      combine(older(p1,m1), newer(p2,m2)) = (p2 + m2*p1, m1*m2)
#pragma unroll
    for (int off = 1; off < 8; off <<= 1) {
        const int dd = off * 8;        // lanes per chunk step
        vf4 pp;
        pp.x = __shfl_up(rp.x, dd, 64);
        pp.y = __shfl_up(rp.y, dd, 64);
        pp.z = __shfl_up(rp.z, dd, 64);
        pp.w = __shfl_up(rp.w, dd, 64);
        const float pm = __shfl_up(rm, dd, 64);
        if (cjw >= off) {
            rp.x += rm * pp.x;
            rp.y += rm * pp.y;
            rp.z += rm * pp.z;
            rp.w += rm * pp.w;
            rm *= pm;
        }
    }

    // ---- Phase B: wave totals -> serial scan over 16 waves (32 lanes)
    if (cjw == 7) {
        *(vf4*)&wtp[wg][qc * 4] = rp;
        wtm8[wg][qc] = rm;
    }
    __syncthreads();
    if (tid < 32) {
        float c = 0.0f;
#pragma unroll
        for (int g = 0; g < 16; ++g) {
            wci[g][tid] = c;
            c = wtp[g][tid] + wtm8[g][tid >> 2] * c;
        }
    }
    __syncthreads();

    // ---- Phase C: per-thread carry-in = excl-in-wave composed on wave carry
    vf4 ep;
    ep.x = __shfl_up(rp.x, 8, 64);
    ep.y = __shfl_up(rp.y, 8, 64);
    ep.z = __shfl_up(rp.z, 8, 64);
    ep.w = __shfl_up(rp.w, 8, 64);
    float em = __shfl_up(rm, 8, 64);
    if (cjw == 0) {
        ep = (vf4){0.f, 0.f, 0.f, 0.f};
        em = 1.0f;
    }
    const vf4 ci = *(const vf4*)&wci[wg][qc * 4];
    vf4 carry;
    carry.x = ep.x + em * ci.x;
    carry.y = ep.y + em * ci.y;
    carry.z = ep.z + em * ci.z;
    carry.w = ep.w + em * ci.w;

    // ---- finalize: param[t] = pl[k] + Mk[k]*carry, pl read back from LDS
#pragma unroll
    for (int k = 0; k < 8; ++k) {
        const int o = off0 + k * DP;
        const vf4 pl = *(const vf4*)(lbase + k * 256 + lane * 4);
        vf4 pv;
        pv.x = pl.x + Mk[k] * carry.x;
        pv.y = pl.y + Mk[k] * carry.y;
        pv.z = pl.z + Mk[k] * carry.z;
        pv.w = pl.w + Mk[k] * carry.w;
        *(vf4*)(param_out + sbase + o) = pv;
    }
}

// ---------------------------------------------------------------------------
extern "C" void kernel_launch(void* const* d_in, const int* in_sizes, int n_in,
                              void* d_out, int out_size, void* d_ws, size_t ws_size,
                              hipStream_t stream)
{
    // 0:y 1:age 2:m(T,D,P) 3:s_raw(T,D,P) 4:a_raw(T-1,D,1) 5:noise(S,T,D,P)
    // 6:cond_sample 7:dim_idx(D) 8:compute_log_prob
    const float* m      = (const float*)d_in[2];
    const float* s_raw  = (const float*)d_in[3];
    const float* a_raw  = (const float*)d_in[4];
    const float* noise  = (const float*)d_in[5];
    const int*   dimidx = (const int*)d_in[7];

    float* param_out = (float*)d_out;
    float* lp_out    = param_out + (size_t)S_DIM * TDP;

    // 128 KB dynamic LDS: 16 waves x 8 k-steps x 64 lanes x 16 B
    fused_scan<<<S_DIM, 1024, 131072, stream>>>(noise, m, s_raw, a_raw, dimidx,
                                                param_out, lp_out);
}